// Round 1
// baseline (139.002 us; speedup 1.0000x reference)
//
#include <hip/hip_runtime.h>
#include <hip/hip_bf16.h>

using short8 = __attribute__((ext_vector_type(8))) short;
using f32x4  = __attribute__((ext_vector_type(4))) float;

#define N_TOK   8192
#define DIM     128
#define JSPLIT  16
#define JCHUNK  (N_TOK / JSPLIT)   // 512
#define NTILES  (JCHUNK / 128)     // 4
#define EXP10F  22026.465794806718f

// ---------------- Kernel A: row-normalize, cast to bf16, pack keys ----------------
__global__ void norm_cast_kernel(const float* __restrict__ feats,
                                 const int* __restrict__ did,
                                 const int* __restrict__ iid,
                                 __hip_bfloat16* __restrict__ xb,
                                 int* __restrict__ keys) {
  const int wid  = threadIdx.x >> 6;
  const int lane = threadIdx.x & 63;
  const int row  = blockIdx.x * 4 + wid;   // one wave per row
  const float2 v = *reinterpret_cast<const float2*>(feats + row * DIM + lane * 2);
  float ss = v.x * v.x + v.y * v.y;
  #pragma unroll
  for (int m = 1; m < 64; m <<= 1) ss += __shfl_xor(ss, m, 64);
  const float scale = 1.0f / fmaxf(sqrtf(ss), 1e-12f);
  __hip_bfloat162 pair;
  pair.x = __float2bfloat16(v.x * scale);
  pair.y = __float2bfloat16(v.y * scale);
  *reinterpret_cast<__hip_bfloat162*>(xb + row * DIM + lane * 2) = pair;
  if (lane == 0) keys[row] = (did[row] << 5) | iid[row];   // did in [0,4), iid in [0,32)
}

// ---------------- Kernel B: fused sim*10 -> exp -> masked row sums ----------------
// Block: 256 thr (4 waves, 2x2), computes 128 i-rows x 512 j-cols (4 tiles of 128).
// A fragments live in registers for the whole block; B tile staged in LDS with
// XOR swizzle (byte ^= (row&7)<<4) to avoid the D=128 row-major bank conflict.
__launch_bounds__(256, 2)
__global__ void sim_kernel(const __hip_bfloat16* __restrict__ xb,
                           const int* __restrict__ keys,
                           float* __restrict__ pos_sum,
                           float* __restrict__ neg_sum) {
  __shared__ __align__(16) char ldsb[128 * 256];  // 128 rows x 256B (swizzled)
  __shared__ int key_sh[128];

  const int js  = blockIdx.x & (JSPLIT - 1);
  const int ib  = blockIdx.x >> 4;           // JSPLIT == 16
  const int tid = threadIdx.x;
  const int lane = tid & 63, wid = tid >> 6;
  const int wm = wid >> 1, wn = wid & 1;     // 2x2 wave grid over 128x128
  const int l15 = lane & 15, l4 = lane >> 4;

  // A fragments: rows ib*128 + wm*64 + m*16 + l15, k = ks*32 + l4*8 (8 contiguous bf16)
  short8 a[4][4];
  const int arow = ib * 128 + wm * 64 + l15;
  #pragma unroll
  for (int m = 0; m < 4; ++m)
    #pragma unroll
    for (int ks = 0; ks < 4; ++ks)
      a[m][ks] = *reinterpret_cast<const short8*>(xb + (arow + m * 16) * DIM + ks * 32 + l4 * 8);

  // Per-lane i-row keys (C/D layout: row = l4*4 + r within each 16x16 fragment)
  int ki[4][4];
  #pragma unroll
  for (int m = 0; m < 4; ++m)
    #pragma unroll
    for (int r = 0; r < 4; ++r)
      ki[m][r] = keys[ib * 128 + wm * 64 + m * 16 + l4 * 4 + r];

  float pos_p[16], neg_p[16];
  #pragma unroll
  for (int t = 0; t < 16; ++t) { pos_p[t] = 0.0f; neg_p[t] = 0.0f; }

  for (int jt = 0; jt < NTILES; ++jt) {
    const int j0 = js * JCHUNK + jt * 128;
    __syncthreads();
    {
      // stage B tile: 128 rows x 256B; thread t -> row t>>1, half t&1 (128B = 8x16B)
      const int row = tid >> 1, half = tid & 1;
      const uint4* src = reinterpret_cast<const uint4*>(xb + (j0 + row) * DIM + half * 64);
      const int rbase = row * 256;
      const int sw = (row & 7) << 4;
      #pragma unroll
      for (int c = 0; c < 8; ++c) {
        const int cb = half * 128 + c * 16;
        *reinterpret_cast<uint4*>(ldsb + rbase + (cb ^ sw)) = src[c];
      }
      if (tid < 128) key_sh[tid] = keys[j0 + tid];
    }
    __syncthreads();

    #pragma unroll
    for (int n = 0; n < 4; ++n) {
      const int rb = wn * 64 + n * 16 + l15;
      const int sw = (rb & 7) << 4;
      short8 b[4];
      #pragma unroll
      for (int ks = 0; ks < 4; ++ks) {
        const int cb = ks * 64 + l4 * 16;
        b[ks] = *reinterpret_cast<const short8*>(ldsb + rb * 256 + (cb ^ sw));
      }
      const int kj = key_sh[rb];
      const int jg = j0 + rb;

      #pragma unroll
      for (int m = 0; m < 4; ++m) {
        f32x4 acc = {0.0f, 0.0f, 0.0f, 0.0f};
        #pragma unroll
        for (int ks = 0; ks < 4; ++ks)
          acc = __builtin_amdgcn_mfma_f32_16x16x32_bf16(a[m][ks], b[ks], acc, 0, 0, 0);
        #pragma unroll
        for (int r = 0; r < 4; ++r) {
          const int ig = ib * 128 + wm * 64 + m * 16 + l4 * 4 + r;
          const float e = __expf(acc[r] * 10.0f);
          const int k_i = ki[m][r];
          if (ig == jg) {
            neg_p[m * 4 + r] += EXP10F;          // diagonal: sim == 1 exactly, weight 1
          } else if (k_i == kj) {
            pos_p[m * 4 + r] += e;               // positive pair
          } else {
            neg_p[m * 4 + r] += (((k_i ^ kj) >> 5) ? 2.0f : 1.0f) * e;  // cross-ds weight 2
          }
        }
      }
    }
  }

  // reduce each per-row partial across the 16 lanes (low 4 bits) holding that row
  #pragma unroll
  for (int t = 0; t < 16; ++t) {
    float p = pos_p[t], q = neg_p[t];
    #pragma unroll
    for (int m = 1; m < 16; m <<= 1) {
      p += __shfl_xor(p, m, 64);
      q += __shfl_xor(q, m, 64);
    }
    if (l15 == 0) {
      const int ig = ib * 128 + wm * 64 + (t >> 2) * 16 + l4 * 4 + (t & 3);
      atomicAdd(&pos_sum[ig], p);
      atomicAdd(&neg_sum[ig], q);
    }
  }
}

// ---------------- Kernel C: per-row loss + masked mean ----------------
__global__ void loss_kernel(const float* __restrict__ pos_sum,
                            const float* __restrict__ neg_sum,
                            float* __restrict__ out) {
  const int tid = threadIdx.x;
  const int lane = tid & 63, wid = tid >> 6;
  float sm = 0.0f, sa = 0.0f;
  int cnt = 0;
  for (int i = tid; i < N_TOK; i += 256) {
    const float p = pos_sum[i], q = neg_sum[i];
    const float loss = -logf(p / (p + q + 1e-8f));
    sa += loss;
    if (p > 0.0f) { sm += loss; cnt++; }
  }
  #pragma unroll
  for (int m = 1; m < 64; m <<= 1) {
    sm += __shfl_xor(sm, m, 64);
    sa += __shfl_xor(sa, m, 64);
    cnt += __shfl_xor(cnt, m, 64);
  }
  __shared__ float r_sm[4], r_sa[4];
  __shared__ int r_c[4];
  if (lane == 0) { r_sm[wid] = sm; r_sa[wid] = sa; r_c[wid] = cnt; }
  __syncthreads();
  if (tid == 0) {
    float tsm = 0.0f, tsa = 0.0f;
    int tc = 0;
    for (int w = 0; w < 4; ++w) { tsm += r_sm[w]; tsa += r_sa[w]; tc += r_c[w]; }
    out[0] = (tc > 0) ? (tsm / (float)tc) : (tsa / (float)N_TOK);
  }
}

extern "C" void kernel_launch(void* const* d_in, const int* in_sizes, int n_in,
                              void* d_out, int out_size, void* d_ws, size_t ws_size,
                              hipStream_t stream) {
  const float* feats = (const float*)d_in[0];
  const int* did = (const int*)d_in[1];
  const int* iid = (const int*)d_in[2];
  float* out = (float*)d_out;

  char* ws = (char*)d_ws;
  __hip_bfloat16* xb = (__hip_bfloat16*)ws;                    // 2 MB
  int* keys   = (int*)(ws + (size_t)N_TOK * DIM * 2);          // 32 KB
  float* pos  = (float*)((char*)keys + N_TOK * 4);             // 32 KB
  float* neg  = pos + N_TOK;                                   // 32 KB

  hipMemsetAsync(pos, 0, (size_t)N_TOK * 2 * sizeof(float), stream);

  norm_cast_kernel<<<N_TOK / 4, 256, 0, stream>>>(feats, did, iid, xb, keys);
  sim_kernel<<<(N_TOK / 128) * JSPLIT, 256, 0, stream>>>(xb, keys, pos, neg);
  loss_kernel<<<1, 256, 0, stream>>>(pos, neg, out);
}